// Round 1
// baseline (639.590 us; speedup 1.0000x reference)
//
#include <hip/hip_runtime.h>
#include <hip/hip_bf16.h>
#include <stdint.h>

#define TOKENS 8192
#define D_IN   2048
#define D_OUT  8192

typedef __attribute__((ext_vector_type(8))) short short8;
typedef __attribute__((ext_vector_type(4))) float floatx4;

// async global->LDS, 16B per lane. LDS dest is wave-uniform base + lane*16.
__device__ __forceinline__ void async_copy16(const void* g, void* l) {
    __builtin_amdgcn_global_load_lds((const __attribute__((address_space(1))) void*)g,
                                     (__attribute__((address_space(3))) void*)l,
                                     16, 0, 0);
}

// ---------------------------------------------------------------------------
// FWHT over last dim (2048) of x [8192,2048] fp32 -> bf16 x_h in workspace.
// One block (256 thr) per row. Bits 8-10 in regs (stride-256 view), bits 0-2
// in regs (consecutive view), bits 3-7 via shfl_xor (t bits 0-4, intra-wave).
// ---------------------------------------------------------------------------
__device__ __forceinline__ void fwht8(float* e) {
#pragma unroll
    for (int s = 1; s < 8; s <<= 1) {
#pragma unroll
        for (int j = 0; j < 8; ++j) {
            if ((j & s) == 0) {
                float a = e[j], b = e[j | s];
                e[j]     = a + b;
                e[j | s] = a - b;
            }
        }
    }
}

__global__ __launch_bounds__(256) void fwht_kernel(const float* __restrict__ x,
                                                   __hip_bfloat16* __restrict__ xh) {
    __shared__ float row[D_IN];
    const int r = blockIdx.x;
    const int t = threadIdx.x;
    const float* xr = x + (size_t)r * D_IN;

    // phase 1: element bits 8..10 (j of stride-256 view)
    float e[8];
#pragma unroll
    for (int j = 0; j < 8; ++j) e[j] = xr[t + 256 * j];   // coalesced per j
    fwht8(e);
#pragma unroll
    for (int j = 0; j < 8; ++j) row[t + 256 * j] = e[j];
    __syncthreads();

    // phase 2: consecutive-8 view: bits 0..2 in regs, bits 3..7 = t bits 0..4
    float f[8];
#pragma unroll
    for (int j = 0; j < 8; ++j) f[j] = row[8 * t + j];
    fwht8(f);
#pragma unroll
    for (int m = 1; m <= 16; m <<= 1) {
#pragma unroll
        for (int j = 0; j < 8; ++j) {
            float v = __shfl_xor(f[j], m, 64);
            f[j] = (t & m) ? (v - f[j]) : (f[j] + v);
        }
    }

    const float scale = 0.02209708691207961f;  // 1/sqrt(2048)
    __hip_bfloat16 ob[8];
#pragma unroll
    for (int j = 0; j < 8; ++j) ob[j] = __float2bfloat16(f[j] * scale);
    __hip_bfloat16* orow = xh + (size_t)r * D_IN + 8 * t;
    *reinterpret_cast<int4*>(orow) = *reinterpret_cast<int4*>(ob);  // 16B store
}

// ---------------------------------------------------------------------------
// Weight fp32 -> bf16 (exact: w values are fp8-e4m3 representable).
// ---------------------------------------------------------------------------
__global__ __launch_bounds__(256) void wconv_kernel(const float* __restrict__ w,
                                                    __hip_bfloat16* __restrict__ wb) {
    const size_t i = ((size_t)blockIdx.x * 256 + threadIdx.x) * 8;
    float4 a = *reinterpret_cast<const float4*>(w + i);
    float4 b = *reinterpret_cast<const float4*>(w + i + 4);
    __hip_bfloat16 ob[8];
    ob[0] = __float2bfloat16(a.x); ob[1] = __float2bfloat16(a.y);
    ob[2] = __float2bfloat16(a.z); ob[3] = __float2bfloat16(a.w);
    ob[4] = __float2bfloat16(b.x); ob[5] = __float2bfloat16(b.y);
    ob[6] = __float2bfloat16(b.z); ob[7] = __float2bfloat16(b.w);
    *reinterpret_cast<int4*>(wb + i) = *reinterpret_cast<int4*>(ob);
}

// ---------------------------------------------------------------------------
// GEMM: C[t,o] = sum_d A[t,d]*B[o,d] + bias[o]. A=x_h bf16, B=w bf16.
// 128x128 tile, BK=32, 256 thr (4 waves, 2x2), wave does 64x64 via 4x4
// mfma_f32_16x16x32_bf16. m97 structure: global_load_lds(16B) + 2 barriers.
// ---------------------------------------------------------------------------
__global__ __launch_bounds__(256) void gemm_kernel(const __hip_bfloat16* __restrict__ A,
                                                   const __hip_bfloat16* __restrict__ B,
                                                   const float* __restrict__ bias,
                                                   float* __restrict__ C) {
    __shared__ __hip_bfloat16 sA[128 * 32];
    __shared__ __hip_bfloat16 sB[128 * 32];

    const int tid  = threadIdx.x;
    const int wave = tid >> 6;
    const int lane = tid & 63;
    const int bm = blockIdx.y;
    const int bn = blockIdx.x;

    const int wm = wave & 1;   // wave row (0..1)
    const int wn = wave >> 1;  // wave col (0..1)
    const int lane16 = lane & 15;
    const int lgrp   = lane >> 4;  // 0..3

    floatx4 acc[4][4];
#pragma unroll
    for (int i = 0; i < 4; ++i)
#pragma unroll
        for (int j = 0; j < 4; ++j) acc[i][j] = 0;

    // staging: tile = 128 rows x 32 cols bf16 = 8KB = 8 instr x 1KB.
    // wave w issues instr w*2+{0,1}; chunk c = instr*64+lane; row=c>>2, kc=c&3.
    const int c0 = (wave * 2 + 0) * 64 + lane;
    const int c1 = (wave * 2 + 1) * 64 + lane;
    const int rA0 = c0 >> 2, kc0 = c0 & 3;
    const int rA1 = c1 >> 2, kc1 = c1 & 3;

    const __hip_bfloat16* gA0 = A + (size_t)(bm * 128 + rA0) * D_IN + kc0 * 8;
    const __hip_bfloat16* gA1 = A + (size_t)(bm * 128 + rA1) * D_IN + kc1 * 8;
    const __hip_bfloat16* gB0 = B + (size_t)(bn * 128 + rA0) * D_IN + kc0 * 8;
    const __hip_bfloat16* gB1 = B + (size_t)(bn * 128 + rA1) * D_IN + kc1 * 8;
    __hip_bfloat16* lA0 = sA + c0 * 8;
    __hip_bfloat16* lA1 = sA + c1 * 8;
    __hip_bfloat16* lB0 = sB + c0 * 8;
    __hip_bfloat16* lB1 = sB + c1 * 8;

    for (int k0 = 0; k0 < D_IN; k0 += 32) {
        async_copy16(gA0 + k0, lA0);
        async_copy16(gA1 + k0, lA1);
        async_copy16(gB0 + k0, lB0);
        async_copy16(gB1 + k0, lB1);
        __syncthreads();  // drains vmcnt(0): LDS tiles ready

        short8 af[4], bf[4];
#pragma unroll
        for (int i = 0; i < 4; ++i) {
            // A frag: A[m=lane&15][k=lgrp*8+j] ; row stride 32 elem (64B)
            af[i] = *reinterpret_cast<const short8*>(sA + (wm * 64 + i * 16 + lane16) * 32 + lgrp * 8);
            bf[i] = *reinterpret_cast<const short8*>(sB + (wn * 64 + i * 16 + lane16) * 32 + lgrp * 8);
        }
#pragma unroll
        for (int i = 0; i < 4; ++i)
#pragma unroll
            for (int j = 0; j < 4; ++j)
                acc[i][j] = __builtin_amdgcn_mfma_f32_16x16x32_bf16(af[i], bf[j], acc[i][j], 0, 0, 0);
        __syncthreads();  // protect LDS from next iter's staging
    }

    // epilogue: C/D layout col=lane&15, row=lgrp*4+r
    float bv[4];
#pragma unroll
    for (int j = 0; j < 4; ++j) bv[j] = bias[bn * 128 + wn * 64 + j * 16 + lane16];

#pragma unroll
    for (int i = 0; i < 4; ++i) {
        const int rbase = bm * 128 + wm * 64 + i * 16 + lgrp * 4;
#pragma unroll
        for (int j = 0; j < 4; ++j) {
            const int col = bn * 128 + wn * 64 + j * 16 + lane16;
#pragma unroll
            for (int r = 0; r < 4; ++r) {
                C[(size_t)(rbase + r) * D_OUT + col] = acc[i][j][r] + bv[j];
            }
        }
    }
}

extern "C" void kernel_launch(void* const* d_in, const int* in_sizes, int n_in,
                              void* d_out, int out_size, void* d_ws, size_t ws_size,
                              hipStream_t stream) {
    const float* x    = (const float*)d_in[0];
    const float* w    = (const float*)d_in[1];
    const float* bias = (const float*)d_in[2];
    float* out = (float*)d_out;

    __hip_bfloat16* xh = (__hip_bfloat16*)d_ws;                      // 32 MB
    __hip_bfloat16* wb = xh + (size_t)TOKENS * D_IN;                 // 32 MB

    fwht_kernel<<<TOKENS, 256, 0, stream>>>(x, xh);
    wconv_kernel<<<(D_OUT * D_IN / 8) / 256, 256, 0, stream>>>(w, wb);
    gemm_kernel<<<dim3(D_OUT / 128, TOKENS / 128), 256, 0, stream>>>(xh, wb, bias, out);
}